// Round 2
// baseline (707.816 us; speedup 1.0000x reference)
//
#include <hip/hip_runtime.h>

#define N_NODES 50000
#define N_EDGES 800000
#define NHID    256
#define NRES_P1 101

// ---------------------------------------------------------------- graph prep

__global__ void k_init(int* __restrict__ deg, int* __restrict__ indeg,
                       float* __restrict__ g) {
    int i = blockIdx.x * 256 + threadIdx.x;
    if (i < N_NODES) { deg[i] = 1; indeg[i] = 1; }   // self-loop pre-counted
    if (i < NHID) g[i] = 0.0f;                       // relu outputs >= 0
}

// edge_index arrives as int32 (harness converts integer inputs to int32)
__global__ void k_count(const int* __restrict__ ei,
                        int* __restrict__ deg, int* __restrict__ indeg) {
    int e = blockIdx.x * 256 + threadIdx.x;
    if (e >= N_EDGES) return;
    int r = ei[e];            // row = source
    int c = ei[N_EDGES + e];  // col = destination
    if ((unsigned)r < N_NODES) atomicAdd(&deg[r], 1);
    if ((unsigned)c < N_NODES) atomicAdd(&indeg[c], 1);
}

// single-block exclusive scan of indeg -> rowptr (and cursor copy)
__global__ __launch_bounds__(1024) void k_scan(const int* __restrict__ cnt,
                                               int* __restrict__ rowptr,
                                               int* __restrict__ cursor) {
    __shared__ int wsum[16];
    __shared__ int wexcl[16];
    __shared__ int ctot;
    __shared__ int carry_s;
    int t = threadIdx.x, lane = t & 63, wid = t >> 6;
    if (t == 0) carry_s = 0;
    __syncthreads();
    for (int base = 0; base < N_NODES; base += 1024) {
        int i = base + t;
        int v = (i < N_NODES) ? cnt[i] : 0;
        int sc = v;
#pragma unroll
        for (int off = 1; off < 64; off <<= 1) {
            int y = __shfl_up(sc, off, 64);
            if (lane >= off) sc += y;
        }
        if (lane == 63) wsum[wid] = sc;
        __syncthreads();
        if (t < 16) {
            int xv = wsum[t];
            int s = xv;
#pragma unroll
            for (int off = 1; off < 16; off <<= 1) {
                int y = __shfl_up(s, off, 64);
                if (t >= off) s += y;
            }
            wexcl[t] = s - xv;
            if (t == 15) ctot = s;
        }
        __syncthreads();
        int carry = carry_s;
        int excl = carry + (sc + wexcl[wid]) - v;
        if (i < N_NODES) { rowptr[i] = excl; cursor[i] = excl; }
        __syncthreads();
        if (t == 0) carry_s = carry + ctot;
    }
}

__global__ void k_fill(const int* __restrict__ ei,
                       int* __restrict__ cursor, int* __restrict__ srcl) {
    int e = blockIdx.x * 256 + threadIdx.x;
    if (e >= N_EDGES + N_NODES) return;
    int r, c;
    if (e < N_EDGES) { r = ei[e]; c = ei[N_EDGES + e]; }
    else             { r = c = e - N_EDGES; }            // self loops
    if ((unsigned)r >= N_NODES || (unsigned)c >= N_NODES) return;
    int pos = atomicAdd(&cursor[c], 1);
    srcl[pos] = r;
}

__global__ void k_dis(const int* __restrict__ deg, float* __restrict__ dis) {
    int i = blockIdx.x * 256 + threadIdx.x;
    if (i < N_NODES) dis[i] = rsqrtf((float)deg[i]);
}

// ---------------------------------------------------------------- dense GEMM
// out[n][j] = dis[n] * ( sum_k A[n][k] * W[k][j] + b[j] ),  K = NHID = 256
// BM=64 BN=64 BK=32, 256 threads, 4x4 microtile. LDS strides padded to 68
// (keeps 16B alignment for ds_read_b128, breaks the power-of-2 bank stride).

#define BK 32
#define LDSS 68

template <bool SPLIT>
__global__ __launch_bounds__(256) void k_gemm(
    const float* __restrict__ A0, const float* __restrict__ A1,
    const float* __restrict__ W, const float* __restrict__ bias,
    const float* __restrict__ dis, float* __restrict__ out, int M) {
    __shared__ float As[BK * LDSS];
    __shared__ float Bs[BK * LDSS];
    const int t = threadIdx.x;
    const int m0 = blockIdx.x * 64;
    const int n0 = blockIdx.y * 64;
    const int tx = t & 15, ty = t >> 4;

    float acc[4][4] = {};

    for (int k0 = 0; k0 < NHID; k0 += BK) {
        // A tile: 64 rows x 32 k, stored transposed As[k][m]
#pragma unroll
        for (int i = 0; i < 8; ++i) {
            int idx = i * 256 + t;
            int m = idx >> 5, k = idx & 31;
            int row = m0 + m;
            float v = 0.0f;
            if (row < M) {
                int kk = k0 + k;
                if (SPLIT) v = (kk < 128) ? A0[row * 128 + kk]
                                          : A1[row * 128 + (kk - 128)];
                else       v = A0[row * NHID + kk];
            }
            As[k * LDSS + m] = v;
        }
        // B tile: 32 k x 64 cols, Bs[k][n]
#pragma unroll
        for (int i = 0; i < 8; ++i) {
            int idx = i * 256 + t;
            int n = idx & 63, kb = idx >> 6;
            Bs[kb * LDSS + n] = W[(k0 + kb) * NHID + n0 + n];
        }
        __syncthreads();
#pragma unroll
        for (int kk = 0; kk < BK; ++kk) {
            const float4 a = *(const float4*)&As[kk * LDSS + (ty << 2)];
            const float4 b = *(const float4*)&Bs[kk * LDSS + (tx << 2)];
            float av[4] = {a.x, a.y, a.z, a.w};
            float bv[4] = {b.x, b.y, b.z, b.w};
#pragma unroll
            for (int r = 0; r < 4; ++r)
#pragma unroll
                for (int c = 0; c < 4; ++c)
                    acc[r][c] = fmaf(av[r], bv[c], acc[r][c]);
        }
        __syncthreads();
    }

    const int nc = n0 + (tx << 2);
    float4 bb = *(const float4*)&bias[nc];
#pragma unroll
    for (int r = 0; r < 4; ++r) {
        int row = m0 + (ty << 2) + r;
        if (row >= M) continue;
        float d = dis[row];
        float4 o;
        o.x = d * (acc[r][0] + bb.x);
        o.y = d * (acc[r][1] + bb.y);
        o.z = d * (acc[r][2] + bb.z);
        o.w = d * (acc[r][3] + bb.w);
        *(float4*)&out[row * NHID + nc] = o;
    }
}

// ----------------------------------------------------------- CSR aggregation
// out[dst][:] = relu( dis[dst] * sum_{src in list(dst)} hs[src][:] )
// one wave per destination node; lane owns 4 contiguous channels.

__global__ __launch_bounds__(256) void k_agg(
    const int* __restrict__ rowptr, const int* __restrict__ rowend,
    const int* __restrict__ srcl, const float* __restrict__ hs,
    const float* __restrict__ dis, float* __restrict__ out) {
    int wave = threadIdx.x >> 6;
    int lane = threadIdx.x & 63;
    int dst = blockIdx.x * 4 + wave;
    if (dst >= N_NODES) return;
    int s = rowptr[dst], e = rowend[dst];
    float4 acc = {0.f, 0.f, 0.f, 0.f};
    for (int k = s; k < e; ++k) {
        int src = srcl[k];
        float4 v = *(const float4*)&hs[src * NHID + (lane << 2)];
        acc.x += v.x; acc.y += v.y; acc.z += v.z; acc.w += v.w;
    }
    float d = dis[dst];
    float4 o;
    o.x = fmaxf(acc.x * d, 0.f);
    o.y = fmaxf(acc.y * d, 0.f);
    o.z = fmaxf(acc.z * d, 0.f);
    o.w = fmaxf(acc.w * d, 0.f);
    *(float4*)&out[dst * NHID + (lane << 2)] = o;
}

// --------------------------------------------------------------- pool + head

__global__ void k_pool(const float* __restrict__ h, float* __restrict__ g) {
    int t = threadIdx.x;  // 256 = channel
    float m = 0.0f;
    for (int n = blockIdx.x; n < N_NODES; n += gridDim.x)
        m = fmaxf(m, h[n * NHID + t]);
    atomicMax((int*)&g[t], __float_as_int(m));  // valid: all values >= 0
}

__global__ __launch_bounds__(128) void k_head(
    const float* __restrict__ g, const float* __restrict__ Wp,
    const float* __restrict__ bp, const float* __restrict__ Wq,
    const float* __restrict__ bq, float* __restrict__ out) {
    __shared__ float sg[NHID];
    __shared__ float red[128];
    int t = threadIdx.x;
    sg[t] = g[t];
    sg[t + 128] = g[t + 128];
    __syncthreads();

    float v = 0.0f;
    if (t < NRES_P1) {
        float acc = bp[t];
        for (int k = 0; k < NHID; ++k) acc = fmaf(sg[k], Wp[k * NRES_P1 + t], acc);
        out[t] = acc;
        v = acc;
    }
    red[t] = (t < NRES_P1) ? v : -1e30f;
    __syncthreads();
#pragma unroll
    for (int off = 64; off > 0; off >>= 1) {
        if (t < off) red[t] = fmaxf(red[t], red[t + off]);
        __syncthreads();
    }
    float mx = red[0];
    __syncthreads();
    float ex = (t < NRES_P1) ? expf(v - mx) : 0.0f;
    red[t] = ex;
    __syncthreads();
#pragma unroll
    for (int off = 64; off > 0; off >>= 1) {
        if (t < off) red[t] += red[t + off];
        __syncthreads();
    }
    float sum = red[0];
    if (t < NRES_P1) out[NRES_P1 + t] = ex / sum;

    if (t < 64) {
        float a = fmaf(sg[t], Wq[t], 0.f);
        a = fmaf(sg[t + 64],  Wq[t + 64],  a);
        a = fmaf(sg[t + 128], Wq[t + 128], a);
        a = fmaf(sg[t + 192], Wq[t + 192], a);
#pragma unroll
        for (int off = 32; off > 0; off >>= 1) a += __shfl_down(a, off, 64);
        if (t == 0) out[2 * NRES_P1] = a + bq[0];
    }
}

// -------------------------------------------------------------------- launch

static inline size_t align256(size_t x) { return (x + 255) & ~size_t(255); }

extern "C" void kernel_launch(void* const* d_in, const int* in_sizes, int n_in,
                              void* d_out, int out_size, void* d_ws,
                              size_t ws_size, hipStream_t stream) {
    (void)in_sizes; (void)n_in; (void)out_size; (void)ws_size;
    const float* x    = (const float*)d_in[0];
    const float* feat = (const float*)d_in[1];
    const int*   ei   = (const int*)d_in[2];   // int32 (harness-converted)
    const float* W1   = (const float*)d_in[3];
    const float* b1   = (const float*)d_in[4];
    const float* W2   = (const float*)d_in[5];
    const float* b2   = (const float*)d_in[6];
    const float* Wp   = (const float*)d_in[7];
    const float* bp   = (const float*)d_in[8];
    const float* Wq   = (const float*)d_in[9];
    const float* bq   = (const float*)d_in[10];
    float* out = (float*)d_out;

    char* ws = (char*)d_ws;
    size_t off = 0;
    auto alloc = [&](size_t bytes) {
        void* p = ws + off;
        off = align256(off + bytes);
        return p;
    };
    int*   deg    = (int*)alloc(4ull * N_NODES);
    int*   indeg  = (int*)alloc(4ull * N_NODES);
    int*   rowptr = (int*)alloc(4ull * (N_NODES + 1));
    int*   cursor = (int*)alloc(4ull * (N_NODES + 1));
    int*   srcl   = (int*)alloc(4ull * (N_EDGES + N_NODES));
    float* dis    = (float*)alloc(4ull * N_NODES);
    float* g      = (float*)alloc(4ull * NHID);
    float* bufA   = (float*)alloc(4ull * N_NODES * NHID);
    float* bufB   = (float*)alloc(4ull * N_NODES * NHID);

    const int nb_nodes = (N_NODES + 255) / 256;

    k_init<<<nb_nodes, 256, 0, stream>>>(deg, indeg, g);
    k_count<<<(N_EDGES + 255) / 256, 256, 0, stream>>>(ei, deg, indeg);
    k_scan<<<1, 1024, 0, stream>>>(indeg, rowptr, cursor);
    k_fill<<<(N_EDGES + N_NODES + 255) / 256, 256, 0, stream>>>(ei, cursor, srcl);
    k_dis<<<nb_nodes, 256, 0, stream>>>(deg, dis);

    dim3 ggrid((N_NODES + 63) / 64, 4);
    // conv1: hs1 = dis .* (concat(x,feat) @ W1 + b1)
    k_gemm<true><<<ggrid, 256, 0, stream>>>(x, feat, W1, b1, dis, bufA, N_NODES);
    // agg1 -> h2 = relu(dis .* gather-sum)
    k_agg<<<(N_NODES + 3) / 4, 256, 0, stream>>>(rowptr, cursor, srcl, bufA, dis, bufB);
    // conv2
    k_gemm<false><<<ggrid, 256, 0, stream>>>(bufB, nullptr, W2, b2, dis, bufA, N_NODES);
    k_agg<<<(N_NODES + 3) / 4, 256, 0, stream>>>(rowptr, cursor, srcl, bufA, dis, bufB);

    k_pool<<<256, 256, 0, stream>>>(bufB, g);
    k_head<<<1, 128, 0, stream>>>(g, Wp, bp, Wq, bq, out);
}

// Round 3
// 501.256 us; speedup vs baseline: 1.4121x; 1.4121x over previous
//
#include <hip/hip_runtime.h>

#define N_NODES 50000
#define N_EDGES 800000
#define NHID    256
#define NRES_P1 101

typedef unsigned short u16;
typedef __attribute__((ext_vector_type(8))) short short8;   // 8 bf16 (guide §3)
typedef __attribute__((ext_vector_type(4))) float f32x4;

static __device__ __forceinline__ u16 f2bf(float f) {       // RNE, no NaN care
    unsigned u = __float_as_uint(f);
    return (u16)((u + 0x7FFF + ((u >> 16) & 1)) >> 16);
}
static __device__ __forceinline__ float bflo(unsigned p) {  // low bf16 of packed
    return __uint_as_float(p << 16);
}
static __device__ __forceinline__ float bfhi(unsigned p) {  // high bf16 of packed
    return __uint_as_float(p & 0xffff0000u);
}

// ---------------------------------------------------------------- graph prep

__global__ void k_init(int* __restrict__ deg, int* __restrict__ indeg,
                       float* __restrict__ g) {
    int i = blockIdx.x * 256 + threadIdx.x;
    if (i < N_NODES) { deg[i] = 1; indeg[i] = 1; }   // self-loop pre-counted
    if (i < NHID) g[i] = 0.0f;                       // relu outputs >= 0
}

__global__ void k_count(const int* __restrict__ ei,
                        int* __restrict__ deg, int* __restrict__ indeg) {
    int e = blockIdx.x * 256 + threadIdx.x;
    if (e >= N_EDGES) return;
    int r = ei[e];            // row = source
    int c = ei[N_EDGES + e];  // col = destination
    if ((unsigned)r < N_NODES) atomicAdd(&deg[r], 1);
    if ((unsigned)c < N_NODES) atomicAdd(&indeg[c], 1);
}

__global__ __launch_bounds__(1024) void k_scan(const int* __restrict__ cnt,
                                               int* __restrict__ rowptr,
                                               int* __restrict__ cursor) {
    __shared__ int wsum[16];
    __shared__ int wexcl[16];
    __shared__ int ctot;
    __shared__ int carry_s;
    int t = threadIdx.x, lane = t & 63, wid = t >> 6;
    if (t == 0) carry_s = 0;
    __syncthreads();
    for (int base = 0; base < N_NODES; base += 1024) {
        int i = base + t;
        int v = (i < N_NODES) ? cnt[i] : 0;
        int sc = v;
#pragma unroll
        for (int off = 1; off < 64; off <<= 1) {
            int y = __shfl_up(sc, off, 64);
            if (lane >= off) sc += y;
        }
        if (lane == 63) wsum[wid] = sc;
        __syncthreads();
        if (t < 16) {
            int xv = wsum[t];
            int s = xv;
#pragma unroll
            for (int off = 1; off < 16; off <<= 1) {
                int y = __shfl_up(s, off, 64);
                if (t >= off) s += y;
            }
            wexcl[t] = s - xv;
            if (t == 15) ctot = s;
        }
        __syncthreads();
        int carry = carry_s;
        int excl = carry + (sc + wexcl[wid]) - v;
        if (i < N_NODES) { rowptr[i] = excl; cursor[i] = excl; }
        __syncthreads();
        if (t == 0) carry_s = carry + ctot;
    }
}

__global__ void k_fill(const int* __restrict__ ei,
                       int* __restrict__ cursor, int* __restrict__ srcl) {
    int e = blockIdx.x * 256 + threadIdx.x;
    if (e >= N_EDGES + N_NODES) return;
    int r, c;
    if (e < N_EDGES) { r = ei[e]; c = ei[N_EDGES + e]; }
    else             { r = c = e - N_EDGES; }            // self loops
    if ((unsigned)r >= N_NODES || (unsigned)c >= N_NODES) return;
    int pos = atomicAdd(&cursor[c], 1);
    srcl[pos] = r;
}

__global__ void k_dis(const int* __restrict__ deg, float* __restrict__ dis) {
    int i = blockIdx.x * 256 + threadIdx.x;
    if (i < N_NODES) dis[i] = rsqrtf((float)deg[i]);
}

// ------------------------------------------------------------ bf16 prep

// A1[n][c] = bf16( c<128 ? x[n][c] : feat[n][c-128] )
__global__ void k_cvtA(const float* __restrict__ x, const float* __restrict__ feat,
                       u16* __restrict__ A1) {
    int q = blockIdx.x * 256 + threadIdx.x;      // quad id
    if (q >= N_NODES * 64) return;
    int n = q >> 6, cq = (q & 63) << 2;
    float4 v = (cq < 128) ? *(const float4*)&x[n * 128 + cq]
                          : *(const float4*)&feat[n * 128 + cq - 128];
    uint2 p;
    p.x = (unsigned)f2bf(v.x) | ((unsigned)f2bf(v.y) << 16);
    p.y = (unsigned)f2bf(v.z) | ((unsigned)f2bf(v.w) << 16);
    *(uint2*)&A1[(size_t)n * 256 + cq] = p;
}

// WT[n][k] = bf16(W[k][n]),  W is [256][256] f32 row-major
__global__ void k_prep_w(const float* __restrict__ W, u16* __restrict__ WT) {
    int tid = blockIdx.x * 256 + threadIdx.x;    // 8192 threads
    if (tid >= 256 * 32) return;
    int n = tid >> 5, k8 = (tid & 31) << 3;
    u16 tmp[8];
#pragma unroll
    for (int i = 0; i < 8; ++i) tmp[i] = f2bf(W[(size_t)(k8 + i) * 256 + n]);
    *(uint4*)&WT[(size_t)n * 256 + k8] = *(uint4*)tmp;
}

// ------------------------------------------------------------- MFMA GEMM
// out[m][n] = bf16( dis[m] * ( sum_k A[m][k] * W[k][n] + bias[n] ) )
// A: [M][256] bf16 row-major.  WT: [256][256] bf16, WT[n][k].
// Block: 256 thr = 2x2 waves; tile 128x128; wave tile 64x64 = 4x4 frags;
// mfma_f32_16x16x32_bf16, BK=32, 8 K-steps.

__global__ __launch_bounds__(256) void k_gemm_mfma(
    const u16* __restrict__ A, const u16* __restrict__ WT,
    const float* __restrict__ bias, const float* __restrict__ dis,
    u16* __restrict__ out, int M) {
    __shared__ u16 As[128][32];
    __shared__ u16 Bs[128][32];
    const int t = threadIdx.x;
    const int m0 = blockIdx.x * 128;
    const int n0 = blockIdx.y * 128;
    const int lane = t & 63;
    const int wave = t >> 6;
    const int wm = wave & 1, wn = wave >> 1;
    const int lr = lane & 15;   // fragment row (A) / col (B) / col (C)
    const int kg = lane >> 4;   // k-group of 8

    f32x4 acc[4][4] = {};

    for (int k0 = 0; k0 < 256; k0 += 32) {
        // stage: 512 chunks of 8 bf16 (16B); 2 chunks per thread; same shape A/B
#pragma unroll
        for (int i = 0; i < 2; ++i) {
            int idx = i * 256 + t;
            int row = idx >> 2;
            int kc = (idx & 3) << 3;
            int grow = m0 + row;
            uint4 va = {0u, 0u, 0u, 0u};
            if (grow < M) va = *(const uint4*)&A[(size_t)grow * 256 + k0 + kc];
            *(uint4*)&As[row][kc] = va;
            uint4 vb = *(const uint4*)&WT[(size_t)(n0 + row) * 256 + k0 + kc];
            *(uint4*)&Bs[row][kc] = vb;
        }
        __syncthreads();
        short8 af[4], bf[4];
#pragma unroll
        for (int mi = 0; mi < 4; ++mi)
            af[mi] = *(const short8*)&As[wm * 64 + mi * 16 + lr][kg * 8];
#pragma unroll
        for (int ni = 0; ni < 4; ++ni)
            bf[ni] = *(const short8*)&Bs[wn * 64 + ni * 16 + lr][kg * 8];
#pragma unroll
        for (int mi = 0; mi < 4; ++mi)
#pragma unroll
            for (int ni = 0; ni < 4; ++ni)
                acc[mi][ni] = __builtin_amdgcn_mfma_f32_16x16x32_bf16(
                    af[mi], bf[ni], acc[mi][ni], 0, 0, 0);
        __syncthreads();
    }

    // epilogue: C/D layout col=lane&15, row=(lane>>4)*4+reg (m89-verified)
    const int orow = m0 + wm * 64;
    const int ocol = n0 + wn * 64;
#pragma unroll
    for (int mi = 0; mi < 4; ++mi) {
#pragma unroll
        for (int r = 0; r < 4; ++r) {
            int row = orow + mi * 16 + kg * 4 + r;
            if (row >= M) continue;
            float d = dis[row];
#pragma unroll
            for (int ni = 0; ni < 4; ++ni) {
                int col = ocol + ni * 16 + lr;
                float v = d * (acc[mi][ni][r] + bias[col]);
                out[(size_t)row * 256 + col] = f2bf(v);
            }
        }
    }
}

// ----------------------------------------------------------- CSR aggregation
// out[dst][:] = relu( dis[dst] * sum_{src} hs[src][:] ),  hs bf16 [N][256]
// one wave per dst; lane owns 4 channels (uint2 = 4 bf16 per gather)

template <bool OUT_BF16>
__global__ __launch_bounds__(256) void k_agg16(
    const int* __restrict__ rowptr, const int* __restrict__ rowend,
    const int* __restrict__ srcl, const u16* __restrict__ hs,
    const float* __restrict__ dis, void* __restrict__ outv) {
    int wave = threadIdx.x >> 6;
    int lane = threadIdx.x & 63;
    int dst = blockIdx.x * 4 + wave;
    if (dst >= N_NODES) return;
    int s = rowptr[dst], e = rowend[dst];
    int ch = lane << 2;
    float a0 = 0.f, a1 = 0.f, a2 = 0.f, a3 = 0.f;
    for (int k = s; k < e; ++k) {
        int src = srcl[k];
        uint2 v = *(const uint2*)&hs[(size_t)src * 256 + ch];
        a0 += bflo(v.x); a1 += bfhi(v.x);
        a2 += bflo(v.y); a3 += bfhi(v.y);
    }
    float d = dis[dst];
    a0 = fmaxf(a0 * d, 0.f); a1 = fmaxf(a1 * d, 0.f);
    a2 = fmaxf(a2 * d, 0.f); a3 = fmaxf(a3 * d, 0.f);
    if (OUT_BF16) {
        uint2 p;
        p.x = (unsigned)f2bf(a0) | ((unsigned)f2bf(a1) << 16);
        p.y = (unsigned)f2bf(a2) | ((unsigned)f2bf(a3) << 16);
        *(uint2*)&((u16*)outv)[(size_t)dst * 256 + ch] = p;
    } else {
        float4 o = {a0, a1, a2, a3};
        *(float4*)&((float*)outv)[(size_t)dst * 256 + ch] = o;
    }
}

// --------------------------------------------------------------- pool + head

__global__ void k_pool(const float* __restrict__ h, float* __restrict__ g) {
    int t = threadIdx.x;  // 256 = channel
    float m = 0.0f;
    for (int n = blockIdx.x; n < N_NODES; n += gridDim.x)
        m = fmaxf(m, h[(size_t)n * NHID + t]);
    atomicMax((int*)&g[t], __float_as_int(m));  // valid: all values >= 0
}

__global__ __launch_bounds__(128) void k_head(
    const float* __restrict__ g, const float* __restrict__ Wp,
    const float* __restrict__ bp, const float* __restrict__ Wq,
    const float* __restrict__ bq, float* __restrict__ out) {
    __shared__ float sg[NHID];
    __shared__ float red[128];
    int t = threadIdx.x;
    sg[t] = g[t];
    sg[t + 128] = g[t + 128];
    __syncthreads();

    float v = 0.0f;
    if (t < NRES_P1) {
        float acc = bp[t];
        for (int k = 0; k < NHID; ++k) acc = fmaf(sg[k], Wp[k * NRES_P1 + t], acc);
        out[t] = acc;
        v = acc;
    }
    red[t] = (t < NRES_P1) ? v : -1e30f;
    __syncthreads();
#pragma unroll
    for (int off = 64; off > 0; off >>= 1) {
        if (t < off) red[t] = fmaxf(red[t], red[t + off]);
        __syncthreads();
    }
    float mx = red[0];
    __syncthreads();
    float ex = (t < NRES_P1) ? expf(v - mx) : 0.0f;
    red[t] = ex;
    __syncthreads();
#pragma unroll
    for (int off = 64; off > 0; off >>= 1) {
        if (t < off) red[t] += red[t + off];
        __syncthreads();
    }
    float sum = red[0];
    if (t < NRES_P1) out[NRES_P1 + t] = ex / sum;

    if (t < 64) {
        float a = fmaf(sg[t], Wq[t], 0.f);
        a = fmaf(sg[t + 64],  Wq[t + 64],  a);
        a = fmaf(sg[t + 128], Wq[t + 128], a);
        a = fmaf(sg[t + 192], Wq[t + 192], a);
#pragma unroll
        for (int off = 32; off > 0; off >>= 1) a += __shfl_down(a, off, 64);
        if (t == 0) out[2 * NRES_P1] = a + bq[0];
    }
}

// -------------------------------------------------------------------- launch

static inline size_t align256(size_t x) { return (x + 255) & ~size_t(255); }

extern "C" void kernel_launch(void* const* d_in, const int* in_sizes, int n_in,
                              void* d_out, int out_size, void* d_ws,
                              size_t ws_size, hipStream_t stream) {
    (void)in_sizes; (void)n_in; (void)out_size; (void)ws_size;
    const float* x    = (const float*)d_in[0];
    const float* feat = (const float*)d_in[1];
    const int*   ei   = (const int*)d_in[2];   // int32 (harness-converted)
    const float* W1   = (const float*)d_in[3];
    const float* b1   = (const float*)d_in[4];
    const float* W2   = (const float*)d_in[5];
    const float* b2   = (const float*)d_in[6];
    const float* Wp   = (const float*)d_in[7];
    const float* bp   = (const float*)d_in[8];
    const float* Wq   = (const float*)d_in[9];
    const float* bq   = (const float*)d_in[10];
    float* out = (float*)d_out;

    char* ws = (char*)d_ws;
    size_t off = 0;
    auto alloc = [&](size_t bytes) {
        void* p = ws + off;
        off = align256(off + bytes);
        return p;
    };
    int*   deg    = (int*)alloc(4ull * N_NODES);
    int*   indeg  = (int*)alloc(4ull * N_NODES);
    int*   rowptr = (int*)alloc(4ull * (N_NODES + 1));
    int*   cursor = (int*)alloc(4ull * (N_NODES + 1));
    int*   srcl   = (int*)alloc(4ull * (N_EDGES + N_NODES));
    float* dis    = (float*)alloc(4ull * N_NODES);
    float* g      = (float*)alloc(4ull * NHID);
    u16*   W1T    = (u16*)alloc(2ull * 256 * 256);
    u16*   W2T    = (u16*)alloc(2ull * 256 * 256);
    u16*   bufA16 = (u16*)alloc(2ull * N_NODES * 256);   // A1, later h3
    float* poolF  = (float*)alloc(4ull * N_NODES * 256); // h1/h2 (bf16), then f32
    u16*   buf1   = (u16*)poolF;                          // h1 (bf16)
    u16*   buf2   = (u16*)poolF + (size_t)N_NODES * 256;  // h2 (bf16)

    const int nb_nodes = (N_NODES + 255) / 256;

    k_init<<<nb_nodes, 256, 0, stream>>>(deg, indeg, g);
    k_count<<<(N_EDGES + 255) / 256, 256, 0, stream>>>(ei, deg, indeg);
    k_scan<<<1, 1024, 0, stream>>>(indeg, rowptr, cursor);
    k_fill<<<(N_EDGES + N_NODES + 255) / 256, 256, 0, stream>>>(ei, cursor, srcl);
    k_dis<<<nb_nodes, 256, 0, stream>>>(deg, dis);

    k_cvtA<<<(N_NODES * 64 + 255) / 256, 256, 0, stream>>>(x, feat, bufA16);
    k_prep_w<<<32, 256, 0, stream>>>(W1, W1T);
    k_prep_w<<<32, 256, 0, stream>>>(W2, W2T);

    dim3 ggrid((N_NODES + 127) / 128, 2);
    // conv1 linear: h1 = bf16(dis .* (A1 @ W1 + b1))
    k_gemm_mfma<<<ggrid, 256, 0, stream>>>(bufA16, W1T, b1, dis, buf1, N_NODES);
    // agg1: h2 = bf16(relu(dis .* gather-sum(h1)))
    k_agg16<true><<<(N_NODES + 3) / 4, 256, 0, stream>>>(rowptr, cursor, srcl,
                                                         buf1, dis, buf2);
    // conv2 linear: h3 = bf16(dis .* (h2 @ W2 + b2))  (reuses A1's buffer)
    k_gemm_mfma<<<ggrid, 256, 0, stream>>>(buf2, W2T, b2, dis, bufA16, N_NODES);
    // agg2: poolF = relu(dis .* gather-sum(h3))  (f32 for pooling precision)
    k_agg16<false><<<(N_NODES + 3) / 4, 256, 0, stream>>>(rowptr, cursor, srcl,
                                                          bufA16, dis, poolF);

    k_pool<<<256, 256, 0, stream>>>(poolF, g);
    k_head<<<1, 128, 0, stream>>>(g, Wp, bp, Wq, bq, out);
}